// Round 8
// baseline (183.093 us; speedup 1.0000x reference)
//
#include <hip/hip_runtime.h>
#include <hip/hip_bf16.h>

#define BATCH 8
#define SEQ   2048
#define DIM   512
#define QB    32
#define KB    64
#define NT    512          // 8 waves
#define NKV   (SEQ / KB)   // 32 KV tiles

typedef __attribute__((ext_vector_type(8))) short short8;
typedef __attribute__((ext_vector_type(4))) float f32x4;
typedef __attribute__((ext_vector_type(4))) unsigned short ushort4v;

__device__ __forceinline__ unsigned short f2bf(float f) {
    union { float f; unsigned u; } v; v.f = f;
    return (unsigned short)((v.u + 0x7FFFu + ((v.u >> 16) & 1u)) >> 16);
}

// Row swizzle for the K/V tile (validated R4-R7). All terms multiples of 8
// elems => 16B chunks stay contiguous under XOR (DMA-compatible).
__device__ __forceinline__ int swz(int kv) {
    return (8 * (kv & 7)) ^ (16 * ((kv >> 3) & 3)) ^ (64 * ((kv >> 3) & 1));
}

// ---- pre-pass: X fp32 -> bf16 once (validated R7 win)
__global__ void to_bf16_kernel(const float* __restrict__ X,
                               unsigned short* __restrict__ Y, int n8) {
    const int i = blockIdx.x * blockDim.x + threadIdx.x;
    if (i >= n8) return;
    const float4 a = ((const float4*)X)[i * 2];
    const float4 b = ((const float4*)X)[i * 2 + 1];
    short8 h;
    h[0] = f2bf(a.x); h[1] = f2bf(a.y); h[2] = f2bf(a.z); h[3] = f2bf(a.w);
    h[4] = f2bf(b.x); h[5] = f2bf(b.y); h[6] = f2bf(b.z); h[7] = f2bf(b.w);
    ((short8*)Y)[i] = h;
}

// Async DMA stage of KV tile t into klds_buf (linear dest, pre-swizzled src).
// Each wave w covers kv rows {k*8+w}; lane covers 16B at swizzled d-offset.
__device__ __forceinline__ void stage_tile(const unsigned short* __restrict__ Xb,
                                           unsigned short* klds_buf,
                                           int t, int w, int lane) {
    const unsigned short* kp = Xb + (size_t)(t * KB) * DIM;
    #pragma unroll
    for (int k = 0; k < 8; ++k) {
        const int kv = k * 8 + w;
        const int dsrc = (lane * 8) ^ swz(kv);               // involution
        const unsigned short* g = kp + (size_t)kv * DIM + dsrc;
        unsigned short* l = klds_buf + kv * DIM;             // wave-uniform base
        __builtin_amdgcn_global_load_lds(
            (__attribute__((address_space(1))) void*)(g),
            (__attribute__((address_space(3))) void*)(l), 16, 0, 0);
    }
}

// score = X·X^T (no scaling), softmax, out = P·X — flash-style, bf16 MFMA.
__global__ __launch_bounds__(NT, 2)
void attn_fwd(const unsigned short* __restrict__ Xbf, float* __restrict__ O) {
    const int b   = blockIdx.x & 7;          // batch -> XCD pinning
    const int qt  = blockIdx.x >> 3;         // 0..63
    const int tid = threadIdx.x;
    const int lane = tid & 63;
    const int w    = tid >> 6;
    const int col  = lane & 15;
    const int kgrp = lane >> 4;

    __shared__ alignas(16) unsigned short Klds[2][KB * DIM];    // 128 KB dbuf
    __shared__ alignas(16) float Sbuf[QB][KB + 4];              // 8.7 KB
    __shared__ alignas(16) unsigned short Pfrag[2][2][64][8];   // 4 KB
    __shared__ float m_s[QB], l_s[QB], fac_s[QB];

    const unsigned short* Xb = Xbf + (size_t)b * SEQ * DIM;

    // ---- Q preload: wave w owns 16 q-rows (strip qs = w>>2), kc strip = w&3
    const int qs = w >> 2;       // 0..1
    const int kc = w & 3;        // 0..3
    short8 qfrag[16];            // 64 VGPR
    {
        const int qrow = qt * QB + qs * 16 + col;
        const unsigned short* qp = Xb + (size_t)qrow * DIM;
        #pragma unroll
        for (int ks = 0; ks < 16; ++ks)
            qfrag[ks] = *(const short8*)(qp + ks * 32 + kgrp * 8);
    }

    if (tid < QB) { m_s[tid] = -INFINITY; l_s[tid] = 0.f; }

    f32x4 oacc[2][4];   // O[32 q][w*64 .. +64 d] : [q2][dt]
    #pragma unroll
    for (int i = 0; i < 2; ++i)
        #pragma unroll
        for (int j = 0; j < 4; ++j)
            oacc[i][j] = (f32x4){0.f, 0.f, 0.f, 0.f};

    // ---- prologue: stage tile 0 -> buf 0
    stage_tile(Xb, &Klds[0][0], 0, w, lane);
    asm volatile("s_waitcnt vmcnt(0)" ::: "memory");
    __syncthreads();   // tile 0 ready (also covers qfrag loads)

    for (int t = 0; t < NKV; ++t) {
        const int cur = t & 1;
        // issue next tile's DMA; lands under QK/softmax/PV compute
        if (t + 1 < NKV) stage_tile(Xb, &Klds[cur ^ 1][0], t + 1, w, lane);

        // ---- QK^T: wave computes S[qs*16 .. +16][kc*16 .. +16]
        {
            const int kvrow = kc * 16 + col;
            const unsigned short* kbase = &Klds[cur][kvrow * DIM];
            const int sw = swz(kvrow);
            f32x4 sacc = (f32x4){0.f,0.f,0.f,0.f};
            #pragma unroll
            for (int ks = 0; ks < 16; ++ks) {
                short8 kfr = *(const short8*)(kbase + ((ks * 32 + kgrp * 8) ^ sw));
                sacc = __builtin_amdgcn_mfma_f32_16x16x32_bf16(qfrag[ks], kfr, sacc, 0, 0, 0);
            }
            #pragma unroll
            for (int r = 0; r < 4; ++r)
                Sbuf[qs * 16 + kgrp * 4 + r][kc * 16 + col] = sacc[r];
        }
        __syncthreads();   // (B) Sbuf ready

        // ---- online softmax: 16 threads/row, 4 scores each
        {
            const int r = tid >> 4;     // 0..31
            const int c = tid & 15;     // 0..15
            float4 sa = *(const float4*)&Sbuf[r][c * 4];
            float mloc = fmaxf(fmaxf(sa.x, sa.y), fmaxf(sa.z, sa.w));
            mloc = fmaxf(mloc, __shfl_xor(mloc, 1));
            mloc = fmaxf(mloc, __shfl_xor(mloc, 2));
            mloc = fmaxf(mloc, __shfl_xor(mloc, 4));
            mloc = fmaxf(mloc, __shfl_xor(mloc, 8));
            const float mold = m_s[r];
            const float mnew = fmaxf(mold, mloc);
            const float fac  = __expf(mold - mnew);   // exp(-inf)=0 on first tile
            float p0 = __expf(sa.x - mnew), p1 = __expf(sa.y - mnew);
            float p2 = __expf(sa.z - mnew), p3 = __expf(sa.w - mnew);
            float lsum = (p0 + p1) + (p2 + p3);
            lsum += __shfl_xor(lsum, 1);
            lsum += __shfl_xor(lsum, 2);
            lsum += __shfl_xor(lsum, 4);
            lsum += __shfl_xor(lsum, 8);
            ushort4v p4;
            p4[0] = f2bf(p0); p4[1] = f2bf(p1); p4[2] = f2bf(p2); p4[3] = f2bf(p3);
            // value (q=r, kv=4c+jj) -> Pfrag[q>>4][kv>>5][(q&15)+16*((kv>>3)&3)][kv&7]
            *(ushort4v*)&Pfrag[r >> 4][c >> 3][(r & 15) + 16 * ((c >> 1) & 3)][(c & 1) * 4] = p4;
            if (c == 0) {
                m_s[r] = mnew;
                fac_s[r] = fac;
                l_s[r] = l_s[r] * fac + lsum;
            }
        }
        __syncthreads();   // (C) Pfrag/fac ready

        // ---- rescale O, then PV: A from Pfrag (lane-contig b128), B via gather
        #pragma unroll
        for (int q2 = 0; q2 < 2; ++q2) {
            #pragma unroll
            for (int r = 0; r < 4; ++r) {
                const float f = fac_s[q2 * 16 + kgrp * 4 + r];
                #pragma unroll
                for (int dt = 0; dt < 4; ++dt) oacc[q2][dt][r] *= f;
            }
        }
        #pragma unroll
        for (int kc2 = 0; kc2 < 2; ++kc2) {
            const int kvb = kc2 * 32 + kgrp * 8;
            short8 afr[2];
            #pragma unroll
            for (int q2 = 0; q2 < 2; ++q2)
                afr[q2] = *(const short8*)&Pfrag[q2][kc2][lane][0];
            #pragma unroll
            for (int dt = 0; dt < 4; ++dt) {
                const int d = w * 64 + dt * 16 + col;
                short8 bfr;
                #pragma unroll
                for (int j = 0; j < 8; ++j) {
                    const int kv = kvb + j;
                    bfr[j] = (short)Klds[cur][kv * DIM + (d ^ swz(kv))];
                }
                #pragma unroll
                for (int q2 = 0; q2 < 2; ++q2)
                    oacc[q2][dt] = __builtin_amdgcn_mfma_f32_16x16x32_bf16(afr[q2], bfr, oacc[q2][dt], 0, 0, 0);
            }
        }

        // ---- end of iter: own DMAs for t+1 done; all waves done reading cur
        asm volatile("s_waitcnt vmcnt(0)" ::: "memory");
        __syncthreads();   // (A)
    }

    // ---- epilogue: divide by l, store fp32
    #pragma unroll
    for (int q2 = 0; q2 < 2; ++q2) {
        #pragma unroll
        for (int r = 0; r < 4; ++r) {
            const int row = q2 * 16 + kgrp * 4 + r;
            const float inv = 1.f / l_s[row];
            float* op = O + ((size_t)b * SEQ + qt * QB + row) * DIM + w * 64 + col;
            #pragma unroll
            for (int dt = 0; dt < 4; ++dt)
                op[dt * 16] = oacc[q2][dt][r] * inv;
        }
    }
}

extern "C" void kernel_launch(void* const* d_in, const int* in_sizes, int n_in,
                              void* d_out, int out_size, void* d_ws, size_t ws_size,
                              hipStream_t stream) {
    const float* X = (const float*)d_in[0];
    float* Out = (float*)d_out;
    unsigned short* Xbf = (unsigned short*)d_ws;   // 16.8 MB bf16 copy

    const int n8 = BATCH * SEQ * DIM / 8;          // 1,048,576
    hipLaunchKernelGGL(to_bf16_kernel, dim3(n8 / 256), dim3(256), 0, stream, X, Xbf, n8);

    dim3 grid(BATCH * (SEQ / QB));                 // 512 blocks
    dim3 block(NT);
    hipLaunchKernelGGL(attn_fwd, grid, block, 0, stream, Xbf, Out);
}